// Round 3
// baseline (314.640 us; speedup 1.0000x reference)
//
#include <hip/hip_runtime.h>

// Problem: B=256, N=8192, K=16, fp32.
// out[b,n,k] = min(y[n], 0.5*(y[n-1]+y[n+1])) - param   (interior n)
//            = y[n] - param                              (n==0 or n==N-1)
// where y = x + param. Pure memory-bound 3-point stencil along N.
//
// V3b: identical to V3, with the nontemporal store done through a native
// clang ext_vector_type(4) float (the builtin rejects HIP_vector_type).
//
// V3 design: keep wave-level per-instruction contiguity (the V2 mistake) AND
// high MLP with no block barrier (the V1 mistake):
//  - lane group g = l>>2 owns row g + j*16 -> every global load/store
//    instruction is one contiguous 1024 B span per wave.
//  - neighbor rows exchanged via a WAVE-PRIVATE LDS tile; no __syncthreads.
//    Intra-wave ds_write->ds_read ordering is handled by compiler lgkmcnt;
//    wave_barrier() pins the program order.
//  - halo rows (wrow0-1, wrow0+WROWS) loaded by lanes 0..3 / 60..63
//    concurrently with the 8 main loads (V1 serialized these after).
//  - nontemporal output stores: keep the 256 MB input set resident in the
//    256 MB L3 across bench iterations instead of letting the 134 MB output
//    stream evict it.

#define B_    256
#define N_    8192
#define KQ    4                       // float4 per n-row (K=16 floats = 64 B)
#define R_    4                       // j-steps per wave
#define WROWS (16 * R_)               // 64 rows per wave
#define TPB   256
#define WAVES (TPB / 64)              // 4 waves per block
#define ROWS_PER_BLK (WROWS * WAVES)  // 256 rows per block
#define TILES (N_ / ROWS_PER_BLK)     // 32 tiles along N

static_assert(TILES == 32, "b = blk >> 5 assumes 32 tiles");

typedef float nfloat4 __attribute__((ext_vector_type(4)));

__device__ __forceinline__ float4 f4add(float4 a, float4 b) {
    return make_float4(a.x + b.x, a.y + b.y, a.z + b.z, a.w + b.w);
}

__device__ __forceinline__ void nt_store(float4* p, float4 v) {
    nfloat4 nv;
    nv.x = v.x; nv.y = v.y; nv.z = v.z; nv.w = v.w;
    __builtin_nontemporal_store(nv, reinterpret_cast<nfloat4*>(p));
}

__global__ __launch_bounds__(TPB)
void convex_kernel(const float4* __restrict__ x4,
                   const float4* __restrict__ p4,
                   float4* __restrict__ o4)
{
    // wave-private tiles: (WROWS+2) rows x 64 B each
    __shared__ float4 lds[WAVES][WROWS + 2][KQ];

    const int tid = threadIdx.x;
    const int w   = tid >> 6;           // wave id 0..3
    const int l   = tid & 63;           // lane
    const int g   = l >> 2;             // row group 0..15
    const int c   = l & 3;              // float4 column 0..3
    const int blk = blockIdx.x;
    const int t   = blk & (TILES - 1);  // tile index along N
    const int b   = blk >> 5;           // batch
    const int wrow0 = t * ROWS_PER_BLK + w * WROWS;  // wave's first row

    // float4 index of (b, wrow0 + g, c). Max ~2^23 -> int ok.
    const int base = (b * N_ + wrow0 + g) * KQ + c;

    // ---- issue ALL global loads back-to-back (halos concurrent, not after)
    const bool topL = (l < 4);          // these lanes fetch row wrow0-1
    const bool botL = (l >= 60);        // these lanes fetch row wrow0+WROWS
    float4 hxv, hpv;
    if (topL | botL) {
        // topL lanes have g=0 (base row = wrow0); botL lanes have g=15.
        int hidx = topL ? (base - ((wrow0 > 0) ? KQ : 0))
                        : (base + ((wrow0 + WROWS < N_) ? (WROWS - 15) * KQ : 0));
        hxv = x4[hidx];
        hpv = p4[hidx];
    }

    float4 xv[R_], pv[R_];
#pragma unroll
    for (int j = 0; j < R_; ++j) {
        xv[j] = x4[base + j * 16 * KQ];
        pv[j] = p4[base + j * 16 * KQ];
    }

    // ---- y = x + param, stage into the wave tile (all contiguous 1024 B ops)
    float4 y[R_];
#pragma unroll
    for (int j = 0; j < R_; ++j) {
        y[j] = f4add(xv[j], pv[j]);
        lds[w][1 + g + j * 16][c] = y[j];
    }
    if (topL | botL) {
        lds[w][topL ? 0 : (WROWS + 1)][c] = f4add(hxv, hpv);
    }

    // Intra-wave only: no __syncthreads needed. wave_barrier pins ordering;
    // lgkmcnt waits are inserted by the compiler for the aliasing ds ops.
    __builtin_amdgcn_wave_barrier();

    // ---- stencil + store
#pragma unroll
    for (int j = 0; j < R_; ++j) {
        const int n = wrow0 + j * 16 + g;
        const float4 yc = y[j];
        const float4 p  = pv[j];
        float4 r;
        if (n == 0 || n == N_ - 1) {
            // Dy padded to 0 at the ends -> out = y - param
            r = make_float4(yc.x - p.x, yc.y - p.y, yc.z - p.z, yc.w - p.w);
        } else {
            const float4 a = lds[w][g + j * 16][c];      // y[n-1]
            const float4 d = lds[w][2 + g + j * 16][c];  // y[n+1]
            const float4 m = make_float4(0.5f * (a.x + d.x), 0.5f * (a.y + d.y),
                                         0.5f * (a.z + d.z), 0.5f * (a.w + d.w));
            r = make_float4(fminf(yc.x, m.x) - p.x,
                            fminf(yc.y, m.y) - p.y,
                            fminf(yc.z, m.z) - p.z,
                            fminf(yc.w, m.w) - p.w);
        }
        nt_store(&o4[base + j * 16 * KQ], r);
    }
}

extern "C" void kernel_launch(void* const* d_in, const int* in_sizes, int n_in,
                              void* d_out, int out_size, void* d_ws, size_t ws_size,
                              hipStream_t stream)
{
    const float4* x = (const float4*)d_in[0];
    const float4* p = (const float4*)d_in[1];
    float4*       o = (float4*)d_out;

    dim3 grid(B_ * TILES);   // 8192 blocks
    dim3 block(TPB);
    convex_kernel<<<grid, block, 0, stream>>>(x, p, o);
}

// Round 4
// 312.295 us; speedup vs baseline: 1.0075x; 1.0075x over previous
//
#include <hip/hip_runtime.h>

// Problem: B=256, N=8192, K=16, fp32.
// out[b,n,k] = min(y[n], 0.5*(y[n-1]+y[n+1])) - param   (interior n)
//            = y[n] - param                              (n==0 or n==N-1)
// where y = x + param. Pure memory-bound 3-point stencil along N.
//
// V4: persistent deep-pipeline kernel. Diagnosis: V1-V3 all had "one
// wave-step per block" structure -> average outstanding memory per CU is
// ~3KB (blocks issue 2 loads, drain at a sync, die). This version keeps
// every wave streaming: each wave owns a contiguous 512-row span and sweeps
// 32 tiles of 16 rows with register prefetch 2 tiles deep (4 loads always
// in flight/wave). No LDS, no barriers. Neighbor exchange via __shfl:
// with lane = g*4+c owning (row g, col c), y[n-1]/y[n+1] live at lane -/+4;
// cross-tile halos are free (top halo = prev tile's row15, bottom halo =
// next tile's row0, both already in registers from the pipeline).
// Every element read exactly once; every load/store one contiguous 1024B
// wave transaction. Plain stores (nt regressed in V3).

#define B_   256
#define N_   8192
#define KQ   4                        // float4 per n-row (K=16 floats)
#define TPB  256
#define GRID 1024
#define NWAVES (GRID * (TPB / 64))    // 4096 waves
#define SPAN 512                      // rows per wave: B_*N_/NWAVES
#define NT   (SPAN / 16)              // 32 tiles per wave
#define TS   (16 * KQ)                // float4 stride per tile (64)

static_assert((long)B_ * N_ == (long)NWAVES * SPAN, "span math");
static_assert(N_ % SPAN == 0, "spans must not cross batch boundary");

__device__ __forceinline__ float4 f4add(float4 a, float4 b) {
    return make_float4(a.x + b.x, a.y + b.y, a.z + b.z, a.w + b.w);
}
__device__ __forceinline__ float4 shfl4(float4 v, int src) {
    return make_float4(__shfl(v.x, src, 64), __shfl(v.y, src, 64),
                       __shfl(v.z, src, 64), __shfl(v.w, src, 64));
}

__global__ __launch_bounds__(TPB)
void convex_kernel(const float4* __restrict__ x4,
                   const float4* __restrict__ p4,
                   float4* __restrict__ o4)
{
    const int tid = threadIdx.x;
    const int w   = tid >> 6;
    const int l   = tid & 63;
    const int g   = l >> 2;            // row group 0..15
    const int c   = l & 3;             // float4 column 0..3
    const int wid = blockIdx.x * (TPB / 64) + w;   // 0..4095
    const int b   = wid >> 4;          // 16 spans per batch row
    const int ns  = (wid & 15) * SPAN; // first n-row of this wave's span

    // float4 index of (b, ns+g, c); addresses stay < 2^23, int is fine.
    const int base0 = (b * N_ + ns + g) * KQ + c;

    // ---- prologue: span-edge halos (row ns-1 for lanes 0..3, row ns+SPAN
    // for lanes 60..63). Clamped values are never consumed (boundary rows
    // n==0 / n==N-1 take the y-param path).
    float4 t        = make_float4(0.f, 0.f, 0.f, 0.f);
    float4 last_bot = make_float4(0.f, 0.f, 0.f, 0.f);
    if (l < 4) {
        const int hr = (ns > 0) ? ns - 1 : ns;
        const int hi = (b * N_ + hr) * KQ + c;
        t = f4add(x4[hi], p4[hi]);
    }
    if (l >= 60) {
        const int br = (ns + SPAN < N_) ? ns + SPAN : N_ - 1;
        const int bi = (b * N_ + br) * KQ + c;
        last_bot = f4add(x4[bi], p4[bi]);
    }

    // ---- prologue: tiles 0 and 1
    float4 xa = x4[base0];
    float4 pa = p4[base0];
    float4 xn = x4[base0 + TS];
    float4 pn = p4[base0 + TS];
    float4 y    = f4add(xa, pa);   // y of current tile
    float4 pcur = pa;              // param of current tile

    const int upL = l - 4;         // lane holding y[n-1] (unused when g==0)
    const int dnL = l + 4;         // lane holding y[n+1] (unused when g==15)
    const int tL  = 60 + c;        // lane holding current tile's row 15
    const int bL  = c;             // lane holding next tile's row 0

#pragma unroll 4
    for (int i = 0; i < NT; ++i) {
        // issue prefetch for tile i+2 (clamped at span end; redundant
        // re-reads of the last tile hit L1)
        const int qi = (i + 2 < NT) ? i + 2 : NT - 1;
        float4 xq = x4[base0 + qi * TS];
        float4 pq = p4[base0 + qi * TS];

        // next tile's y (vmcnt wait covers loads issued 2 iterations ago;
        // the just-issued prefetch stays in flight)
        float4 yn = f4add(xn, pn);

        // bottom halo: next tile's row 0 (or the span-edge halo last iter)
        float4 bot = shfl4(yn, bL);
        if (i == NT - 1) bot = last_bot;          // valid in lanes 60..63

        float4 a = shfl4(y, upL);
        float4 d = shfl4(y, dnL);
        if (g == 0)  a = t;                       // top halo
        if (g == 15) d = bot;

        const int n = ns + i * 16 + g;
        float4 r;
        if (n == 0 || n == N_ - 1) {
            // Dy padded to 0 at the ends -> out = y - param
            r = make_float4(y.x - pcur.x, y.y - pcur.y,
                            y.z - pcur.z, y.w - pcur.w);
        } else {
            const float4 m = make_float4(0.5f * (a.x + d.x), 0.5f * (a.y + d.y),
                                         0.5f * (a.z + d.z), 0.5f * (a.w + d.w));
            r = make_float4(fminf(y.x, m.x) - pcur.x,
                            fminf(y.y, m.y) - pcur.y,
                            fminf(y.z, m.z) - pcur.z,
                            fminf(y.w, m.w) - pcur.w);
        }
        o4[base0 + i * TS] = r;

        // rotate pipeline: save top halo for next tile, advance registers
        t    = shfl4(y, tL);
        y    = yn;
        pcur = pn;
        xn   = xq;
        pn   = pq;
    }
}

extern "C" void kernel_launch(void* const* d_in, const int* in_sizes, int n_in,
                              void* d_out, int out_size, void* d_ws, size_t ws_size,
                              hipStream_t stream)
{
    const float4* x = (const float4*)d_in[0];
    const float4* p = (const float4*)d_in[1];
    float4*       o = (float4*)d_out;

    dim3 grid(GRID);    // 1024 blocks = 4096 waves, 16 waves/CU, no tail
    dim3 block(TPB);
    convex_kernel<<<grid, block, 0, stream>>>(x, p, o);
}

// Round 5
// 305.971 us; speedup vs baseline: 1.0283x; 1.0207x over previous
//
#include <hip/hip_runtime.h>

// Problem: B=256, N=8192, K=16, fp32.
// out[b,n,k] = min(y[n], 0.5*(y[n-1]+y[n+1])) - param   (interior n)
//            = y[n] - param                              (n==0 or n==N-1)
// where y = x + param. Pure memory-bound 3-point stencil along N.
//
// V5 = V1 (measured best, 105.6 us) + ONE change: non-temporal output
// stores. Theory: FETCH_SIZE ~= half the 268 MB input set because the
// 134 MB output stream flushes inputs out of the 256 MB Infinity Cache
// every iteration. Output is written once, never read -> pure pollution.
// nt stores keep inputs L3-resident across bench iterations: FETCH should
// collapse and the read side runs at L3 speed.

#define B_    256
#define N_    8192
#define K_    16
#define TILE  64          // n-rows per block
#define KQ    4           // K/4 float4 columns per row
#define NTILES (N_ / TILE) // 128

typedef float nfloat4 __attribute__((ext_vector_type(4)));

__device__ __forceinline__ void nt_store(float4* p, float4 v) {
    nfloat4 nv;
    nv.x = v.x; nv.y = v.y; nv.z = v.z; nv.w = v.w;
    __builtin_nontemporal_store(nv, reinterpret_cast<nfloat4*>(p));
}

__global__ __launch_bounds__(256)
void convex_kernel(const float4* __restrict__ x4,
                   const float4* __restrict__ p4,
                   float4* __restrict__ o4)
{
    // y-tile with 1-row halo on each side: 66 rows x 4 float4 = 4224 B LDS
    __shared__ float4 ysh[TILE + 2][KQ];

    const int tid = threadIdx.x;
    const int row = tid >> 2;     // 0..63 : n-row within tile
    const int col = tid & 3;      // 0..3  : float4 column within K
    const int blk = blockIdx.x;
    const int t   = blk & (NTILES - 1);  // tile index along N
    const int b   = blk >> 7;            // batch (NTILES == 128)
    const int n0  = t * TILE;

    const long base = ((long)b * N_ + n0) * KQ;   // float4 index of tile origin
    const long idx  = base + (long)row * KQ + col;

    // Main load: each element of x/param read exactly once.
    float4 xv = x4[idx];
    float4 pv = p4[idx];
    float4 yv = make_float4(xv.x + pv.x, xv.y + pv.y, xv.z + pv.z, xv.w + pv.w);
    ysh[row + 1][col] = yv;

    // Halo rows: n0-1 (lanes 0..3) and n0+TILE (lanes 4..7), guarded at the
    // array ends (those values are never consumed there: boundary rows take
    // the y-param path).
    if (tid < 8) {
        const int c = tid & 3;
        float4 h = make_float4(0.f, 0.f, 0.f, 0.f);
        if (tid < 4) {
            if (n0 > 0) {
                float4 hx = x4[base - KQ + c];
                float4 hp = p4[base - KQ + c];
                h = make_float4(hx.x + hp.x, hx.y + hp.y, hx.z + hp.z, hx.w + hp.w);
            }
            ysh[0][c] = h;
        } else {
            if (n0 + TILE < N_) {
                float4 hx = x4[base + (long)TILE * KQ + c];
                float4 hp = p4[base + (long)TILE * KQ + c];
                h = make_float4(hx.x + hp.x, hx.y + hp.y, hx.z + hp.z, hx.w + hp.w);
            }
            ysh[TILE + 1][c] = h;
        }
    }
    __syncthreads();

    const int n = n0 + row;
    float4 r;
    if (n == 0 || n == N_ - 1) {
        // Dy padded to 0 at the ends -> out = y - param
        r = make_float4(yv.x - pv.x, yv.y - pv.y, yv.z - pv.z, yv.w - pv.w);
    } else {
        float4 a = ysh[row][col];      // y[n-1]
        float4 d = ysh[row + 2][col];  // y[n+1]
        float4 m = make_float4(0.5f * (a.x + d.x), 0.5f * (a.y + d.y),
                               0.5f * (a.z + d.z), 0.5f * (a.w + d.w));
        r = make_float4(fminf(yv.x, m.x) - pv.x,
                        fminf(yv.y, m.y) - pv.y,
                        fminf(yv.z, m.z) - pv.z,
                        fminf(yv.w, m.w) - pv.w);
    }
    nt_store(&o4[idx], r);
}

extern "C" void kernel_launch(void* const* d_in, const int* in_sizes, int n_in,
                              void* d_out, int out_size, void* d_ws, size_t ws_size,
                              hipStream_t stream)
{
    const float4* x = (const float4*)d_in[0];
    const float4* p = (const float4*)d_in[1];
    float4*       o = (float4*)d_out;

    dim3 grid(B_ * NTILES);   // 32768 blocks
    dim3 block(256);
    convex_kernel<<<grid, block, 0, stream>>>(x, p, o);
}